// Round 1
// baseline (772.186 us; speedup 1.0000x reference)
//
#include <hip/hip_runtime.h>

static constexpr int TPB = 256;

// -------------------- per-node inverse L2 norm --------------------
template<int F>
__global__ void norm_kernel(const float* __restrict__ feat, float* __restrict__ inv, int n) {
    constexpr int LPN = (F >= 64) ? 64 : F;   // lanes per node
    constexpr int EPL = F / LPN;              // elems per lane
    int gid = blockIdx.x * TPB + threadIdx.x;
    int node = gid / LPN;
    int lane = gid % LPN;
    if (node >= n) return;
    const float* fr = feat + (size_t)node * F;
    float s = 0.f;
#pragma unroll
    for (int k = 0; k < EPL; ++k) {
        float v = fr[lane + k * LPN];
        s += v * v;
    }
#pragma unroll
    for (int off = LPN / 2; off > 0; off >>= 1)
        s += __shfl_xor(s, off);
    if (lane == 0) inv[node] = (s > 0.f) ? rsqrtf(s) : 1.0f;
}

// -------------------- edge cosine similarity + threshold; accumulate rs, deg --------------------
template<int F>
__global__ void sim_kernel(const float* __restrict__ feat, const float* __restrict__ inv,
                           const int* __restrict__ row, const int* __restrict__ col,
                           float* __restrict__ sim, float* __restrict__ rs, float* __restrict__ deg,
                           long long ne) {
    constexpr int LPE = F / 4;                // lanes per edge (float4 each)
    long long gid = (long long)blockIdx.x * TPB + threadIdx.x;
    long long e = gid / LPE;
    int lane = (int)(gid % LPE);
    if (e >= ne) return;
    int r = row[e], c = col[e];
    const float4 a = *(const float4*)(feat + (size_t)r * F + lane * 4);
    const float4 b = *(const float4*)(feat + (size_t)c * F + lane * 4);
    float s = a.x * b.x + a.y * b.y + a.z * b.z + a.w * b.w;
#pragma unroll
    for (int off = LPE / 2; off > 0; off >>= 1)
        s += __shfl_xor(s, off);
    if (lane == 0) {
        s *= inv[r] * inv[c];
        if (s < 0.5f || r == c) s = 0.f;
        sim[e] = s;
        if (s > 0.f) {
            atomicAdd(&rs[r], s);
            atomicAdd(&deg[r], 1.0f);
        }
    }
}

// -------------------- att = sim / rs[row]; w = exp(att) (in place over sim) --------------------
__global__ void att_w_kernel(float* __restrict__ ew, const float* __restrict__ rs,
                             const int* __restrict__ row, long long ne) {
    long long e = (long long)blockIdx.x * TPB + threadIdx.x;
    if (e >= ne) return;
    float s = ew[e];
    ew[e] = (s > 0.f) ? __expf(s / rs[row[e]]) : 0.f;
}

// -------------------- tail self-loop weights: w[E-N+i] = exp(1/(deg[i]+1)) --------------------
__global__ void selfw_kernel(const float* __restrict__ deg, float* __restrict__ ew,
                             long long erand, int n) {
    int i = blockIdx.x * TPB + threadIdx.x;
    if (i >= n) return;
    ew[erand + i] = __expf(1.0f / (deg[i] + 1.0f));
}

// -------------------- deg2[c] = sum of w over col --------------------
__global__ void deg2_kernel(const float* __restrict__ ew, const int* __restrict__ col,
                            float* __restrict__ deg2, long long ne) {
    long long e = (long long)blockIdx.x * TPB + threadIdx.x;
    if (e >= ne) return;
    float we = ew[e];
    if (we != 0.f) atomicAdd(&deg2[col[e]], we);
}

__global__ void dis_kernel(const float* __restrict__ deg2, float* __restrict__ dis, int n) {
    int i = blockIdx.x * TPB + threadIdx.x;
    if (i >= n) return;
    float d = deg2[i];
    dis[i] = (d > 0.f) ? rsqrtf(d) : 0.f;
}

// -------------------- dense h = feat @ W  (W staged in LDS) --------------------
template<int FIN, int FOUT, int NPB>
__global__ void matmul_kernel(const float* __restrict__ feat, const float* __restrict__ W,
                              float* __restrict__ out, int n) {
    __shared__ float Wl[FIN * FOUT];
    for (int i = threadIdx.x; i < FIN * FOUT; i += TPB) Wl[i] = W[i];
    __syncthreads();
    constexpr int SLOTS = TPB / FOUT;
    int j = threadIdx.x % FOUT;
    int sub = threadIdx.x / FOUT;
    int base = blockIdx.x * NPB;
    for (int nn = sub; nn < NPB; nn += SLOTS) {
        int node = base + nn;
        if (node >= n) return;
        const float* fr = feat + (size_t)node * FIN;
        float acc = 0.f;
#pragma unroll
        for (int k = 0; k < FIN; ++k) acc += fr[k] * Wl[k * FOUT + j];
        out[(size_t)node * FOUT + j] = acc;
    }
}

// -------------------- out[col] += dis[row]*w*dis[col] * h[row] --------------------
template<int F>
__global__ void aggregate_kernel(const float* __restrict__ h, const float* __restrict__ w,
                                 const float* __restrict__ dis,
                                 const int* __restrict__ row, const int* __restrict__ col,
                                 float* __restrict__ out, long long ne) {
    constexpr int LPE = F / 4;
    long long gid = (long long)blockIdx.x * TPB + threadIdx.x;
    long long e = gid / LPE;
    int lane = (int)(gid % LPE);
    if (e >= ne) return;
    float we = w[e];
    if (we == 0.f) return;
    int r = row[e], c = col[e];
    float nw = dis[r] * we * dis[c];
    if (nw == 0.f) return;
    const float4 hv = *(const float4*)(h + (size_t)r * F + lane * 4);
    float* op = out + (size_t)c * F + lane * 4;
    atomicAdd(op + 0, nw * hv.x);
    atomicAdd(op + 1, nw * hv.y);
    atomicAdd(op + 2, nw * hv.z);
    atomicAdd(op + 3, nw * hv.w);
}

// -------------------- bias (+ optional relu) --------------------
template<int F, bool RELU>
__global__ void bias_kernel(float* __restrict__ out, const float* __restrict__ b, long long total) {
    long long gid = (long long)blockIdx.x * TPB + threadIdx.x;
    if (gid >= total) return;
    int j = (int)(gid % F);
    float v = out[gid] + b[j];
    if (RELU) v = fmaxf(v, 0.f);
    out[gid] = v;
}

// -------------------- row-wise log_softmax (F=16), in place --------------------
__global__ void logsoftmax_kernel(float* __restrict__ o, int n) {
    int i = blockIdx.x * TPB + threadIdx.x;
    if (i >= n) return;
    float* p = o + (size_t)i * 16;
    float v[16];
#pragma unroll
    for (int k = 0; k < 4; ++k) {
        float4 t = *(float4*)(p + 4 * k);
        v[4 * k] = t.x; v[4 * k + 1] = t.y; v[4 * k + 2] = t.z; v[4 * k + 3] = t.w;
    }
    float m = v[0];
#pragma unroll
    for (int k = 1; k < 16; ++k) m = fmaxf(m, v[k]);
    float s = 0.f;
#pragma unroll
    for (int k = 0; k < 16; ++k) s += expf(v[k] - m);
    float ls = m + logf(s);
#pragma unroll
    for (int k = 0; k < 4; ++k) {
        float4 t = make_float4(v[4 * k] - ls, v[4 * k + 1] - ls, v[4 * k + 2] - ls, v[4 * k + 3] - ls);
        *(float4*)(p + 4 * k) = t;
    }
}

// =====================================================================
template<int FIN, int FOUT, bool RELU>
static void run_layer(const float* feat, const float* W, const float* b,
                      float* h, float* outb,
                      const int* row, const int* col, int N, long long E,
                      float* ew, float* inv, float* rs, float* deg, float* deg2, float* dis,
                      hipStream_t stream) {
    // zero rs, deg, deg2 (contiguous)
    hipMemsetAsync(rs, 0, sizeof(float) * 3 * (size_t)N, stream);

    {   // norms
        constexpr int LPN = (FIN >= 64) ? 64 : FIN;
        long long t = (long long)N * LPN;
        norm_kernel<FIN><<<(unsigned)((t + TPB - 1) / TPB), TPB, 0, stream>>>(feat, inv, N);
    }
    {   // edge similarity
        constexpr int LPE = FIN / 4;
        long long t = E * LPE;
        sim_kernel<FIN><<<(unsigned)((t + TPB - 1) / TPB), TPB, 0, stream>>>(feat, inv, row, col, ew, rs, deg, E);
    }
    att_w_kernel<<<(unsigned)((E + TPB - 1) / TPB), TPB, 0, stream>>>(ew, rs, row, E);
    selfw_kernel<<<(unsigned)((N + TPB - 1) / TPB), TPB, 0, stream>>>(deg, ew, E - N, N);
    deg2_kernel<<<(unsigned)((E + TPB - 1) / TPB), TPB, 0, stream>>>(ew, col, deg2, E);
    dis_kernel<<<(unsigned)((N + TPB - 1) / TPB), TPB, 0, stream>>>(deg2, dis, N);

    matmul_kernel<FIN, FOUT, 64><<<(unsigned)((N + 63) / 64), TPB, 0, stream>>>(feat, W, h, N);

    hipMemsetAsync(outb, 0, sizeof(float) * (size_t)N * FOUT, stream);
    {
        constexpr int LPA = FOUT / 4;
        long long t = E * LPA;
        aggregate_kernel<FOUT><<<(unsigned)((t + TPB - 1) / TPB), TPB, 0, stream>>>(h, ew, dis, row, col, outb, E);
    }
    bias_kernel<FOUT, RELU><<<(unsigned)(((long long)N * FOUT + TPB - 1) / TPB), TPB, 0, stream>>>(outb, b, (long long)N * FOUT);
}

extern "C" void kernel_launch(void* const* d_in, const int* in_sizes, int n_in,
                              void* d_out, int out_size, void* d_ws, size_t ws_size,
                              hipStream_t stream) {
    const float* x  = (const float*)d_in[0];
    const int*   row = (const int*)d_in[1];
    const int*   col = (const int*)d_in[2];
    const float* W0 = (const float*)d_in[3];
    const float* b0 = (const float*)d_in[4];
    const float* W1 = (const float*)d_in[5];
    const float* b1 = (const float*)d_in[6];
    const float* W2 = (const float*)d_in[7];
    const float* b2 = (const float*)d_in[8];

    const int NFEAT = 128, NHID = 128;
    int N = in_sizes[0] / NFEAT;            // 50000
    long long E = in_sizes[1];              // 850000

    float* ws = (float*)d_ws;
    float* A    = ws;                        // [N,128] matmul result
    float* B    = A + (size_t)N * NHID;      // [N,128] layer output / next feat
    float* ew   = B + (size_t)N * NHID;      // [E] sim -> w
    float* inv  = ew + E;                    // [N]
    float* rs   = inv + N;                   // [N]
    float* deg  = rs + N;                    // [N]
    float* deg2 = deg + N;                   // [N]
    float* dis  = deg2 + N;                  // [N]
    float* out  = (float*)d_out;             // [N,16]

    // layer 0: x[N,128] -> B[N,128], relu
    run_layer<128, 128, true >(x, W0, b0, A, B,   row, col, N, E, ew, inv, rs, deg, deg2, dis, stream);
    // layer 1: B[N,128] -> B[N,16] (A holds h1), relu
    run_layer<128, 16,  true >(B, W1, b1, A, B,   row, col, N, E, ew, inv, rs, deg, deg2, dis, stream);
    // layer 2: B[N,16] -> out[N,16], no relu
    run_layer<16,  16,  false>(B, W2, b2, A, out, row, col, N, E, ew, inv, rs, deg, deg2, dis, stream);

    logsoftmax_kernel<<<(unsigned)((N + TPB - 1) / TPB), TPB, 0, stream>>>(out, N);
}

// Round 2
// 705.411 us; speedup vs baseline: 1.0947x; 1.0947x over previous
//
#include <hip/hip_runtime.h>

static constexpr int TPB = 256;

// -------------------- per-node inverse L2 norm --------------------
template<int F>
__global__ void norm_kernel(const float* __restrict__ feat, float* __restrict__ inv, int n) {
    constexpr int LPN = (F >= 64) ? 64 : F;   // lanes per node
    constexpr int EPL = F / LPN;              // elems per lane
    int gid = blockIdx.x * TPB + threadIdx.x;
    int node = gid / LPN;
    int lane = gid % LPN;
    if (node >= n) return;
    const float* fr = feat + (size_t)node * F;
    float s = 0.f;
#pragma unroll
    for (int k = 0; k < EPL; ++k) {
        float v = fr[lane + k * LPN];
        s += v * v;
    }
#pragma unroll
    for (int off = LPN / 2; off > 0; off >>= 1)
        s += __shfl_xor(s, off);
    if (lane == 0) inv[node] = (s > 0.f) ? rsqrtf(s) : 1.0f;
}

// -------------------- edge cosine similarity + threshold; accumulate rs, deg --------------------
template<int F>
__global__ void sim_kernel(const float* __restrict__ feat, const float* __restrict__ inv,
                           const int* __restrict__ row, const int* __restrict__ col,
                           float* __restrict__ sim, float* __restrict__ rs, float* __restrict__ deg,
                           long long ne) {
    constexpr int LPE = F / 4;                // lanes per edge (float4 each)
    long long gid = (long long)blockIdx.x * TPB + threadIdx.x;
    long long e = gid / LPE;
    int lane = (int)(gid % LPE);
    if (e >= ne) return;
    int r = row[e], c = col[e];
    const float4 a = *(const float4*)(feat + (size_t)r * F + lane * 4);
    const float4 b = *(const float4*)(feat + (size_t)c * F + lane * 4);
    float s = a.x * b.x + a.y * b.y + a.z * b.z + a.w * b.w;
#pragma unroll
    for (int off = LPE / 2; off > 0; off >>= 1)
        s += __shfl_xor(s, off);
    if (lane == 0) {
        s *= inv[r] * inv[c];
        if (s < 0.5f || r == c) s = 0.f;
        sim[e] = s;
        if (s > 0.f) {
            atomicAdd(&rs[r], s);
            atomicAdd(&deg[r], 1.0f);
        }
    }
}

// -------------------- att = sim / rs[row]; w = exp(att) (in place over sim) --------------------
__global__ void att_w_kernel(float* __restrict__ ew, const float* __restrict__ rs,
                             const int* __restrict__ row, long long ne) {
    long long e = (long long)blockIdx.x * TPB + threadIdx.x;
    if (e >= ne) return;
    float s = ew[e];
    ew[e] = (s > 0.f) ? __expf(s / rs[row[e]]) : 0.f;
}

// -------------------- tail self-loop weights: w[E-N+i] = exp(1/(deg[i]+1)) --------------------
__global__ void selfw_kernel(const float* __restrict__ deg, float* __restrict__ ew,
                             long long erand, int n) {
    int i = blockIdx.x * TPB + threadIdx.x;
    if (i >= n) return;
    ew[erand + i] = __expf(1.0f / (deg[i] + 1.0f));
}

// -------------------- deg2[c] = sum of w over col --------------------
__global__ void deg2_kernel(const float* __restrict__ ew, const int* __restrict__ col,
                            float* __restrict__ deg2, long long ne) {
    long long e = (long long)blockIdx.x * TPB + threadIdx.x;
    if (e >= ne) return;
    float we = ew[e];
    if (we != 0.f) atomicAdd(&deg2[col[e]], we);
}

__global__ void dis_kernel(const float* __restrict__ deg2, float* __restrict__ dis, int n) {
    int i = blockIdx.x * TPB + threadIdx.x;
    if (i >= n) return;
    float d = deg2[i];
    dis[i] = (d > 0.f) ? rsqrtf(d) : 0.f;
}

// -------------------- dense h = feat @ W, FIN=FOUT=128: LDS-tiled GEMM --------------------
// Block: 64 nodes x 128 cols. W fully staged (64KB), feat tile (32KB).
// 256 threads: j4 = tid%32 (4 cols via float4), sub = tid/32 (8 nodes each).
// Per 4-k chunk: 12 ds_read_b128 vs 128 FMA -> FMA-issue-bound.
__global__ __launch_bounds__(256) void gemm128_kernel(const float* __restrict__ feat,
                                                      const float* __restrict__ W,
                                                      float* __restrict__ out, int n) {
    constexpr int FIN = 128, FOUT = 128, BM = 64;
    __shared__ float Wl[FIN * FOUT];          // 64 KB
    __shared__ float Fl[BM * FIN];            // 32 KB
    int tid = threadIdx.x;
    int base = blockIdx.x * BM;
    {   // stage W (coalesced float4)
        const float4* Wg = (const float4*)W;
        float4* Ws = (float4*)Wl;
        for (int i = tid; i < FIN * FOUT / 4; i += 256) Ws[i] = Wg[i];
    }
    {   // stage feat tile (zero-pad the tail block)
        const float4* Fg = (const float4*)(feat + (size_t)base * FIN);
        float4* Fs = (float4*)Fl;
        int maxv = (n - base) * (FIN / 4);
        for (int i = tid; i < BM * FIN / 4; i += 256)
            Fs[i] = (i < maxv) ? Fg[i] : make_float4(0.f, 0.f, 0.f, 0.f);
    }
    __syncthreads();

    int j4 = tid & 31;          // 32 col-groups of 4
    int sub = tid >> 5;         // 8 node-groups of 8
    float4 acc[8];
#pragma unroll
    for (int s = 0; s < 8; ++s) acc[s] = make_float4(0.f, 0.f, 0.f, 0.f);

    for (int k = 0; k < FIN; k += 4) {
        float4 w0 = *(const float4*)&Wl[(k + 0) * FOUT + j4 * 4];
        float4 w1 = *(const float4*)&Wl[(k + 1) * FOUT + j4 * 4];
        float4 w2 = *(const float4*)&Wl[(k + 2) * FOUT + j4 * 4];
        float4 w3 = *(const float4*)&Wl[(k + 3) * FOUT + j4 * 4];
#pragma unroll
        for (int s = 0; s < 8; ++s) {
            float4 f = *(const float4*)&Fl[(sub * 8 + s) * FIN + k];
            acc[s].x += f.x * w0.x + f.y * w1.x + f.z * w2.x + f.w * w3.x;
            acc[s].y += f.x * w0.y + f.y * w1.y + f.z * w2.y + f.w * w3.y;
            acc[s].z += f.x * w0.z + f.y * w1.z + f.z * w2.z + f.w * w3.z;
            acc[s].w += f.x * w0.w + f.y * w1.w + f.z * w2.w + f.w * w3.w;
        }
    }
#pragma unroll
    for (int s = 0; s < 8; ++s) {
        int node = base + sub * 8 + s;
        if (node < n)
            *(float4*)(out + (size_t)node * FOUT + j4 * 4) = acc[s];
    }
}

// -------------------- small dense matmul (FIN=16) --------------------
template<int FIN, int FOUT, int NPB>
__global__ void matmul_kernel(const float* __restrict__ feat, const float* __restrict__ W,
                              float* __restrict__ out, int n) {
    __shared__ float Wl[FIN * FOUT];
    for (int i = threadIdx.x; i < FIN * FOUT; i += TPB) Wl[i] = W[i];
    __syncthreads();
    constexpr int SLOTS = TPB / FOUT;
    int j = threadIdx.x % FOUT;
    int sub = threadIdx.x / FOUT;
    int base = blockIdx.x * NPB;
    for (int nn = sub; nn < NPB; nn += SLOTS) {
        int node = base + nn;
        if (node >= n) return;
        const float* fr = feat + (size_t)node * FIN;
        float acc = 0.f;
#pragma unroll
        for (int k = 0; k < FIN; ++k) acc += fr[k] * Wl[k * FOUT + j];
        out[(size_t)node * FOUT + j] = acc;
    }
}

// -------------------- out[col] += dis[row]*w*dis[col] * h[row] --------------------
template<int F>
__global__ void aggregate_kernel(const float* __restrict__ h, const float* __restrict__ w,
                                 const float* __restrict__ dis,
                                 const int* __restrict__ row, const int* __restrict__ col,
                                 float* __restrict__ out, long long ne) {
    constexpr int LPE = F / 4;
    long long gid = (long long)blockIdx.x * TPB + threadIdx.x;
    long long e = gid / LPE;
    int lane = (int)(gid % LPE);
    if (e >= ne) return;
    float we = w[e];
    if (we == 0.f) return;
    int r = row[e], c = col[e];
    float nw = dis[r] * we * dis[c];
    if (nw == 0.f) return;
    const float4 hv = *(const float4*)(h + (size_t)r * F + lane * 4);
    float* op = out + (size_t)c * F + lane * 4;
    atomicAdd(op + 0, nw * hv.x);
    atomicAdd(op + 1, nw * hv.y);
    atomicAdd(op + 2, nw * hv.z);
    atomicAdd(op + 3, nw * hv.w);
}

// -------------------- bias (+ optional relu) --------------------
template<int F, bool RELU>
__global__ void bias_kernel(float* __restrict__ out, const float* __restrict__ b, long long total) {
    long long gid = (long long)blockIdx.x * TPB + threadIdx.x;
    if (gid >= total) return;
    int j = (int)(gid % F);
    float v = out[gid] + b[j];
    if (RELU) v = fmaxf(v, 0.f);
    out[gid] = v;
}

// -------------------- row-wise log_softmax (F=16), in place --------------------
__global__ void logsoftmax_kernel(float* __restrict__ o, int n) {
    int i = blockIdx.x * TPB + threadIdx.x;
    if (i >= n) return;
    float* p = o + (size_t)i * 16;
    float v[16];
#pragma unroll
    for (int k = 0; k < 4; ++k) {
        float4 t = *(float4*)(p + 4 * k);
        v[4 * k] = t.x; v[4 * k + 1] = t.y; v[4 * k + 2] = t.z; v[4 * k + 3] = t.w;
    }
    float m = v[0];
#pragma unroll
    for (int k = 1; k < 16; ++k) m = fmaxf(m, v[k]);
    float s = 0.f;
#pragma unroll
    for (int k = 0; k < 16; ++k) s += expf(v[k] - m);
    float ls = m + logf(s);
#pragma unroll
    for (int k = 0; k < 4; ++k) {
        float4 t = make_float4(v[4 * k] - ls, v[4 * k + 1] - ls, v[4 * k + 2] - ls, v[4 * k + 3] - ls);
        *(float4*)(p + 4 * k) = t;
    }
}

// =====================================================================
template<int FIN, int FOUT, bool RELU>
static void run_layer(const float* feat, const float* W, const float* b,
                      float* h, float* outb,
                      const int* row, const int* col, int N, long long E,
                      float* ew, float* inv, float* rs, float* deg, float* deg2, float* dis,
                      hipStream_t stream) {
    // zero rs, deg, deg2 (contiguous)
    hipMemsetAsync(rs, 0, sizeof(float) * 3 * (size_t)N, stream);

    {   // norms
        constexpr int LPN = (FIN >= 64) ? 64 : FIN;
        long long t = (long long)N * LPN;
        norm_kernel<FIN><<<(unsigned)((t + TPB - 1) / TPB), TPB, 0, stream>>>(feat, inv, N);
    }
    {   // edge similarity
        constexpr int LPE = FIN / 4;
        long long t = E * LPE;
        sim_kernel<FIN><<<(unsigned)((t + TPB - 1) / TPB), TPB, 0, stream>>>(feat, inv, row, col, ew, rs, deg, E);
    }
    att_w_kernel<<<(unsigned)((E + TPB - 1) / TPB), TPB, 0, stream>>>(ew, rs, row, E);
    selfw_kernel<<<(unsigned)((N + TPB - 1) / TPB), TPB, 0, stream>>>(deg, ew, E - N, N);
    deg2_kernel<<<(unsigned)((E + TPB - 1) / TPB), TPB, 0, stream>>>(ew, col, deg2, E);
    dis_kernel<<<(unsigned)((N + TPB - 1) / TPB), TPB, 0, stream>>>(deg2, dis, N);

    if (FIN == 128 && FOUT == 128) {
        gemm128_kernel<<<(unsigned)((N + 63) / 64), 256, 0, stream>>>(feat, W, h, N);
    } else {
        matmul_kernel<FIN, FOUT, 64><<<(unsigned)((N + 63) / 64), TPB, 0, stream>>>(feat, W, h, N);
    }

    hipMemsetAsync(outb, 0, sizeof(float) * (size_t)N * FOUT, stream);
    {
        constexpr int LPA = FOUT / 4;
        long long t = E * LPA;
        aggregate_kernel<FOUT><<<(unsigned)((t + TPB - 1) / TPB), TPB, 0, stream>>>(h, ew, dis, row, col, outb, E);
    }
    bias_kernel<FOUT, RELU><<<(unsigned)(((long long)N * FOUT + TPB - 1) / TPB), TPB, 0, stream>>>(outb, b, (long long)N * FOUT);
}

extern "C" void kernel_launch(void* const* d_in, const int* in_sizes, int n_in,
                              void* d_out, int out_size, void* d_ws, size_t ws_size,
                              hipStream_t stream) {
    const float* x  = (const float*)d_in[0];
    const int*   row = (const int*)d_in[1];
    const int*   col = (const int*)d_in[2];
    const float* W0 = (const float*)d_in[3];
    const float* b0 = (const float*)d_in[4];
    const float* W1 = (const float*)d_in[5];
    const float* b1 = (const float*)d_in[6];
    const float* W2 = (const float*)d_in[7];
    const float* b2 = (const float*)d_in[8];

    const int NFEAT = 128, NHID = 128;
    int N = in_sizes[0] / NFEAT;            // 50000
    long long E = in_sizes[1];              // 850000

    float* ws = (float*)d_ws;
    float* A    = ws;                        // [N,128] matmul result
    float* B    = A + (size_t)N * NHID;      // [N,128] layer output / next feat
    float* ew   = B + (size_t)N * NHID;      // [E] sim -> w
    float* inv  = ew + E;                    // [N]
    float* rs   = inv + N;                   // [N]
    float* deg  = rs + N;                    // [N]
    float* deg2 = deg + N;                   // [N]
    float* dis  = deg2 + N;                  // [N]
    float* out  = (float*)d_out;             // [N,16]

    // layer 0: x[N,128] -> B[N,128], relu
    run_layer<128, 128, true >(x, W0, b0, A, B,   row, col, N, E, ew, inv, rs, deg, deg2, dis, stream);
    // layer 1: B[N,128] -> B[N,16] (A holds h1), relu
    run_layer<128, 16,  true >(B, W1, b1, A, B,   row, col, N, E, ew, inv, rs, deg, deg2, dis, stream);
    // layer 2: B[N,16] -> out[N,16], no relu
    run_layer<16,  16,  false>(B, W2, b2, A, out, row, col, N, E, ew, inv, rs, deg, deg2, dis, stream);

    logsoftmax_kernel<<<(unsigned)((N + TPB - 1) / TPB), TPB, 0, stream>>>(out, N);
}

// Round 3
// 567.239 us; speedup vs baseline: 1.3613x; 1.2436x over previous
//
#include <hip/hip_runtime.h>

static constexpr int TPB = 256;

// -------------------- per-node inverse L2 norm --------------------
template<int F>
__global__ void norm_kernel(const float* __restrict__ feat, float* __restrict__ inv, int n) {
    constexpr int LPN = (F >= 64) ? 64 : F;   // lanes per node
    constexpr int EPL = F / LPN;              // elems per lane
    int gid = blockIdx.x * TPB + threadIdx.x;
    int node = gid / LPN;
    int lane = gid % LPN;
    if (node >= n) return;
    const float* fr = feat + (size_t)node * F;
    float s = 0.f;
#pragma unroll
    for (int k = 0; k < EPL; ++k) {
        float v = fr[lane + k * LPN];
        s += v * v;
    }
#pragma unroll
    for (int off = LPN / 2; off > 0; off >>= 1)
        s += __shfl_xor(s, off);
    if (lane == 0) inv[node] = (s > 0.f) ? rsqrtf(s) : 1.0f;
}

// -------------------- edge cosine sim (2 edges/thread for MLP), accumulate rs, deg --------------------
template<int F>
__global__ void sim_kernel(const float* __restrict__ feat, const float* __restrict__ inv,
                           const int* __restrict__ row, const int* __restrict__ col,
                           float* __restrict__ sim, float* __restrict__ rs, float* __restrict__ deg,
                           long long ne) {
    constexpr int LPE = (F >= 128) ? 16 : (F / 4);   // lanes per edge
    constexpr int NV  = F / LPE / 4;                 // float4 per lane per side (128->2, 16->1)
    long long half = (ne + 1) >> 1;
    long long gid = (long long)blockIdx.x * TPB + threadIdx.x;
    long long slot = gid / LPE;
    int lane = (int)(gid % LPE);
    if (slot >= half) return;
    long long e0 = slot;
    long long e1 = slot + half;
    bool has1 = (e1 < ne);
    int r0 = row[e0], c0 = col[e0];
    int r1 = has1 ? (int)row[e1] : r0;
    int c1 = has1 ? (int)col[e1] : c0;
    const float4* a0p = (const float4*)(feat + (size_t)r0 * F) + lane * NV;
    const float4* b0p = (const float4*)(feat + (size_t)c0 * F) + lane * NV;
    const float4* a1p = (const float4*)(feat + (size_t)r1 * F) + lane * NV;
    const float4* b1p = (const float4*)(feat + (size_t)c1 * F) + lane * NV;
    float4 av0[NV], bv0[NV], av1[NV], bv1[NV];
#pragma unroll
    for (int k = 0; k < NV; ++k) { av0[k] = a0p[k]; bv0[k] = b0p[k]; av1[k] = a1p[k]; bv1[k] = b1p[k]; }
    float s0 = 0.f, s1 = 0.f;
#pragma unroll
    for (int k = 0; k < NV; ++k) {
        s0 += av0[k].x * bv0[k].x + av0[k].y * bv0[k].y + av0[k].z * bv0[k].z + av0[k].w * bv0[k].w;
        s1 += av1[k].x * bv1[k].x + av1[k].y * bv1[k].y + av1[k].z * bv1[k].z + av1[k].w * bv1[k].w;
    }
#pragma unroll
    for (int off = LPE / 2; off > 0; off >>= 1) {
        s0 += __shfl_xor(s0, off);
        s1 += __shfl_xor(s1, off);
    }
    if (lane == 0) {
        s0 *= inv[r0] * inv[c0];
        if (s0 < 0.5f || r0 == c0) s0 = 0.f;
        sim[e0] = s0;
        if (s0 > 0.f) { atomicAdd(&rs[r0], s0); atomicAdd(&deg[r0], 1.0f); }
        if (has1) {
            s1 *= inv[r1] * inv[c1];
            if (s1 < 0.5f || r1 == c1) s1 = 0.f;
            sim[e1] = s1;
            if (s1 > 0.f) { atomicAdd(&rs[r1], s1); atomicAdd(&deg[r1], 1.0f); }
        }
    }
}

// -------------------- fused: w = exp(att) (or self formula for tail); deg2[col] += w --------------------
__global__ void weights_kernel(float* __restrict__ ew, const float* __restrict__ rs,
                               const float* __restrict__ deg, const int* __restrict__ row,
                               const int* __restrict__ col, float* __restrict__ deg2,
                               long long ne, int n) {
    long long e = (long long)blockIdx.x * TPB + threadIdx.x;
    if (e >= ne) return;
    long long ss = ne - n;     // self-loop tail start
    float w;
    if (e >= ss) {
        w = __expf(1.0f / (deg[(int)(e - ss)] + 1.0f));
    } else {
        float s = ew[e];
        w = (s > 0.f) ? __expf(s / rs[row[e]]) : 0.f;
    }
    ew[e] = w;
    if (w != 0.f) atomicAdd(&deg2[col[e]], w);
}

// -------------------- dense h = feat @ W, FIN=FOUT=128: LDS-tiled GEMM --------------------
__global__ __launch_bounds__(256) void gemm128_kernel(const float* __restrict__ feat,
                                                      const float* __restrict__ W,
                                                      float* __restrict__ out, int n) {
    constexpr int FIN = 128, FOUT = 128, BM = 64;
    __shared__ float Wl[FIN * FOUT];          // 64 KB
    __shared__ float Fl[BM * FIN];            // 32 KB
    int tid = threadIdx.x;
    int base = blockIdx.x * BM;
    {
        const float4* Wg = (const float4*)W;
        float4* Ws = (float4*)Wl;
        for (int i = tid; i < FIN * FOUT / 4; i += 256) Ws[i] = Wg[i];
    }
    {
        const float4* Fg = (const float4*)(feat + (size_t)base * FIN);
        float4* Fs = (float4*)Fl;
        int maxv = (n - base) * (FIN / 4);
        for (int i = tid; i < BM * FIN / 4; i += 256)
            Fs[i] = (i < maxv) ? Fg[i] : make_float4(0.f, 0.f, 0.f, 0.f);
    }
    __syncthreads();

    int j4 = tid & 31;
    int sub = tid >> 5;
    float4 acc[8];
#pragma unroll
    for (int s = 0; s < 8; ++s) acc[s] = make_float4(0.f, 0.f, 0.f, 0.f);

    for (int k = 0; k < FIN; k += 4) {
        float4 w0 = *(const float4*)&Wl[(k + 0) * FOUT + j4 * 4];
        float4 w1 = *(const float4*)&Wl[(k + 1) * FOUT + j4 * 4];
        float4 w2 = *(const float4*)&Wl[(k + 2) * FOUT + j4 * 4];
        float4 w3 = *(const float4*)&Wl[(k + 3) * FOUT + j4 * 4];
#pragma unroll
        for (int s = 0; s < 8; ++s) {
            float4 f = *(const float4*)&Fl[(sub * 8 + s) * FIN + k];
            acc[s].x += f.x * w0.x + f.y * w1.x + f.z * w2.x + f.w * w3.x;
            acc[s].y += f.x * w0.y + f.y * w1.y + f.z * w2.y + f.w * w3.y;
            acc[s].z += f.x * w0.z + f.y * w1.z + f.z * w2.z + f.w * w3.z;
            acc[s].w += f.x * w0.w + f.y * w1.w + f.z * w2.w + f.w * w3.w;
        }
    }
#pragma unroll
    for (int s = 0; s < 8; ++s) {
        int node = base + sub * 8 + s;
        if (node < n)
            *(float4*)(out + (size_t)node * FOUT + j4 * 4) = acc[s];
    }
}

// -------------------- small dense matmul (FIN=16) --------------------
template<int FIN, int FOUT, int NPB>
__global__ void matmul_kernel(const float* __restrict__ feat, const float* __restrict__ W,
                              float* __restrict__ out, int n) {
    __shared__ float Wl[FIN * FOUT];
    for (int i = threadIdx.x; i < FIN * FOUT; i += TPB) Wl[i] = W[i];
    __syncthreads();
    constexpr int SLOTS = TPB / FOUT;
    int j = threadIdx.x % FOUT;
    int sub = threadIdx.x / FOUT;
    int base = blockIdx.x * NPB;
    for (int nn = sub; nn < NPB; nn += SLOTS) {
        int node = base + nn;
        if (node >= n) return;
        const float* fr = feat + (size_t)node * FIN;
        float acc = 0.f;
#pragma unroll
        for (int k = 0; k < FIN; ++k) acc += fr[k] * Wl[k * FOUT + j];
        out[(size_t)node * FOUT + j] = acc;
    }
}

// -------------------- random-edge aggregate: out[col] += dis[row]*w*dis[col]*h[row] --------------------
template<int F>
__global__ void aggregate_kernel(const float* __restrict__ h, const float* __restrict__ w,
                                 const float* __restrict__ deg2,
                                 const int* __restrict__ row, const int* __restrict__ col,
                                 float* __restrict__ out, long long nrand) {
    constexpr int LPE = F / 4;
    long long gid = (long long)blockIdx.x * TPB + threadIdx.x;
    long long e = gid / LPE;
    int lane = (int)(gid % LPE);
    if (e >= nrand) return;
    float we = w[e];
    if (we == 0.f) return;
    int r = row[e], c = col[e];
    float dr = deg2[r], dc = deg2[c];
    if (dr <= 0.f || dc <= 0.f) return;
    float nw = rsqrtf(dr) * we * rsqrtf(dc);
    const float4 hv = *(const float4*)(h + (size_t)r * F + lane * 4);
    float* op = out + (size_t)c * F + lane * 4;
    atomicAdd(op + 0, nw * hv.x);
    atomicAdd(op + 1, nw * hv.y);
    atomicAdd(op + 2, nw * hv.z);
    atomicAdd(op + 3, nw * hv.w);
}

// -------------------- finalize F=128: out = (relu)(agg + (w_self/deg2)*h + b) --------------------
template<bool RELU>
__global__ void finalize128_kernel(float* __restrict__ agg, const float* __restrict__ h,
                                   const float* __restrict__ ws_self, const float* __restrict__ deg2,
                                   const float* __restrict__ b, int n) {
    int gid = blockIdx.x * TPB + threadIdx.x;
    int node = gid >> 5;
    int j4 = gid & 31;
    if (node >= n) return;
    float d = deg2[node];
    float nw = (d > 0.f) ? ws_self[node] / d : 0.f;   // dis^2 * w_self
    float4 hv = *((const float4*)(h + (size_t)node * 128) + j4);
    float4 o  = *((float4*)(agg + (size_t)node * 128) + j4);
    float4 bv = ((const float4*)b)[j4];
    o.x += nw * hv.x + bv.x;
    o.y += nw * hv.y + bv.y;
    o.z += nw * hv.z + bv.z;
    o.w += nw * hv.w + bv.w;
    if (RELU) {
        o.x = fmaxf(o.x, 0.f); o.y = fmaxf(o.y, 0.f);
        o.z = fmaxf(o.z, 0.f); o.w = fmaxf(o.w, 0.f);
    }
    *((float4*)(agg + (size_t)node * 128) + j4) = o;
}

// -------------------- finalize F=16 (one thread per node), optional relu / log_softmax --------------------
template<bool RELU, bool LOGSM>
__global__ void finalize16_kernel(const float* __restrict__ agg, const float* __restrict__ h,
                                  const float* __restrict__ ws_self, const float* __restrict__ deg2,
                                  const float* __restrict__ b, float* __restrict__ out, int n) {
    int node = blockIdx.x * TPB + threadIdx.x;
    if (node >= n) return;
    float d = deg2[node];
    float nw = (d > 0.f) ? ws_self[node] / d : 0.f;
    float v[16];
#pragma unroll
    for (int k = 0; k < 4; ++k) {
        float4 a = *((const float4*)(agg + (size_t)node * 16) + k);
        float4 hv = *((const float4*)(h + (size_t)node * 16) + k);
        float4 bv = ((const float4*)b)[k];
        v[4 * k + 0] = a.x + nw * hv.x + bv.x;
        v[4 * k + 1] = a.y + nw * hv.y + bv.y;
        v[4 * k + 2] = a.z + nw * hv.z + bv.z;
        v[4 * k + 3] = a.w + nw * hv.w + bv.w;
    }
    if (RELU) {
#pragma unroll
        for (int k = 0; k < 16; ++k) v[k] = fmaxf(v[k], 0.f);
    }
    if (LOGSM) {
        float m = v[0];
#pragma unroll
        for (int k = 1; k < 16; ++k) m = fmaxf(m, v[k]);
        float s = 0.f;
#pragma unroll
        for (int k = 0; k < 16; ++k) s += expf(v[k] - m);
        float ls = m + logf(s);
#pragma unroll
        for (int k = 0; k < 16; ++k) v[k] -= ls;
    }
#pragma unroll
    for (int k = 0; k < 4; ++k) {
        float4 t = make_float4(v[4 * k], v[4 * k + 1], v[4 * k + 2], v[4 * k + 3]);
        *((float4*)(out + (size_t)node * 16) + k) = t;
    }
}

// =====================================================================
// Per-layer driver. agg buffer = outb; h buffer separate. FOUT=128 -> finalize128 (in place on outb),
// FOUT=16 -> finalize16 writes `fin_out`.
template<int FIN, int FOUT, bool RELU, bool LOGSM>
static void run_layer(const float* feat, const float* W, const float* b,
                      float* h, float* outb, float* fin_out,
                      const int* row, const int* col, int N, long long E,
                      float* ew, float* inv, float* rs, float* deg, float* deg2,
                      hipStream_t stream) {
    hipMemsetAsync(rs, 0, sizeof(float) * 3 * (size_t)N, stream);   // rs, deg, deg2 contiguous

    {   // norms
        constexpr int LPN = (FIN >= 64) ? 64 : FIN;
        long long t = (long long)N * LPN;
        norm_kernel<FIN><<<(unsigned)((t + TPB - 1) / TPB), TPB, 0, stream>>>(feat, inv, N);
    }
    {   // edge similarity (2 edges per thread)
        constexpr int LPE = (FIN >= 128) ? 16 : (FIN / 4);
        long long half = (E + 1) >> 1;
        long long t = half * LPE;
        sim_kernel<FIN><<<(unsigned)((t + TPB - 1) / TPB), TPB, 0, stream>>>(feat, inv, row, col, ew, rs, deg, E);
    }
    weights_kernel<<<(unsigned)((E + TPB - 1) / TPB), TPB, 0, stream>>>(ew, rs, deg, row, col, deg2, E, N);

    if (FIN == 128 && FOUT == 128) {
        gemm128_kernel<<<(unsigned)((N + 63) / 64), 256, 0, stream>>>(feat, W, h, N);
    } else {
        matmul_kernel<FIN, FOUT, 64><<<(unsigned)((N + 63) / 64), TPB, 0, stream>>>(feat, W, h, N);
    }

    hipMemsetAsync(outb, 0, sizeof(float) * (size_t)N * FOUT, stream);
    {
        long long nrand = E - N;
        constexpr int LPA = FOUT / 4;
        long long t = nrand * LPA;
        aggregate_kernel<FOUT><<<(unsigned)((t + TPB - 1) / TPB), TPB, 0, stream>>>(h, ew, deg2, row, col, outb, nrand);
    }
    const float* ws_self = ew + (E - N);
    if (FOUT == 128) {
        long long t = (long long)N * 32;
        finalize128_kernel<RELU><<<(unsigned)((t + TPB - 1) / TPB), TPB, 0, stream>>>(outb, h, ws_self, deg2, b, N);
    } else {
        finalize16_kernel<RELU, LOGSM><<<(unsigned)((N + TPB - 1) / TPB), TPB, 0, stream>>>(outb, h, ws_self, deg2, b, fin_out, N);
    }
}

extern "C" void kernel_launch(void* const* d_in, const int* in_sizes, int n_in,
                              void* d_out, int out_size, void* d_ws, size_t ws_size,
                              hipStream_t stream) {
    const float* x  = (const float*)d_in[0];
    const int*   row = (const int*)d_in[1];
    const int*   col = (const int*)d_in[2];
    const float* W0 = (const float*)d_in[3];
    const float* b0 = (const float*)d_in[4];
    const float* W1 = (const float*)d_in[5];
    const float* b1 = (const float*)d_in[6];
    const float* W2 = (const float*)d_in[7];
    const float* b2 = (const float*)d_in[8];

    const int NFEAT = 128, NHID = 128;
    int N = in_sizes[0] / NFEAT;            // 50000
    long long E = in_sizes[1];              // 850000

    float* ws = (float*)d_ws;
    float* A    = ws;                        // [N,128] h (matmul result)
    float* B    = A + (size_t)N * NHID;      // [N,128] layer output / next feat
    float* ew   = B + (size_t)N * NHID;      // [E] sim -> w
    float* inv  = ew + E;                    // [N]
    float* rs   = inv + N;                   // [N]
    float* deg  = rs + N;                    // [N]
    float* deg2 = deg + N;                   // [N]
    float* out  = (float*)d_out;             // [N,16]

    // layer 0: x[N,128] -> B[N,128], relu
    run_layer<128, 128, true,  false>(x, W0, b0, A, B, B,   row, col, N, E, ew, inv, rs, deg, deg2, stream);
    // layer 1: B[N,128] -> B[N,16] (h in A, agg in B reused), relu
    run_layer<128, 16,  true,  false>(B, W1, b1, A, B, B,   row, col, N, E, ew, inv, rs, deg, deg2, stream);
    // layer 2: B[N,16] -> out[N,16], log_softmax
    run_layer<16,  16,  false, true >(B, W2, b2, A, B, out, row, col, N, E, ew, inv, rs, deg, deg2, stream);
}